// Round 16
// baseline (279.157 us; speedup 1.0000x reference)
//
#include <hip/hip_runtime.h>

typedef unsigned short u16;
typedef unsigned int u32;
typedef __attribute__((ext_vector_type(8))) short short8;
typedef __attribute__((ext_vector_type(4))) float f32x4;
typedef __attribute__((ext_vector_type(16))) float f32x16;
typedef __attribute__((ext_vector_type(4))) u32 u32x4;

typedef __attribute__((address_space(3))) unsigned int as3u32;
typedef __attribute__((address_space(1))) unsigned int as1u32;

__device__ __forceinline__ void gld16(void* lds, const void* g) {
    __builtin_amdgcn_global_load_lds((as1u32*)(void*)g, (as3u32*)lds, 16, 0, 0);
}

__device__ inline float bf2f(u16 u) {
    u32 v = ((u32)u) << 16;
    return __builtin_bit_cast(float, v);
}
__device__ inline u16 f2bf(float f) {
    u32 u = __builtin_bit_cast(u32, f);
    u32 r = u + 0x7FFF + ((u >> 16) & 1);   // round-to-nearest-even
    return (u16)(r >> 16);
}
__device__ __forceinline__ u32 cvtpk_bf16(float lo, float hi) {
    u32 r;
    asm("v_cvt_pk_bf16_f32 %0, %1, %2" : "=v"(r) : "v"(lo), "v"(hi));
    return r;
}
__device__ inline void unpack8(uint4 v, float* f) {
    u32 a[4] = {v.x, v.y, v.z, v.w};
#pragma unroll
    for (int i = 0; i < 4; ++i) {
        f[2 * i]     = bf2f((u16)(a[i] & 0xffff));
        f[2 * i + 1] = bf2f((u16)(a[i] >> 16));
    }
}

// ---------------- fused prep: x cast | weight transpose+cast | rope tables ----------------
__global__ __launch_bounds__(256) void prep_all(const float* __restrict__ x,
                                                const float* __restrict__ Wq,
                                                const float* __restrict__ Wk,
                                                const float* __restrict__ Wv,
                                                const float* __restrict__ Wo,
                                                u16* __restrict__ Xbf,
                                                u16* __restrict__ Wtqkv,
                                                u16* __restrict__ Wot,
                                                float* __restrict__ cosb,
                                                float* __restrict__ sinb) {
    __shared__ float tile[64][65];
    const int bx = blockIdx.x;
    const int t = threadIdx.x;
    if (bx < 4096) {                     // ---- cast x ----
        int i = (bx * 256 + t) * 8;
        float4 a = *(const float4*)&x[i];
        float4 b = *(const float4*)&x[i + 4];
        u16 o[8];
        o[0] = f2bf(a.x); o[1] = f2bf(a.y); o[2] = f2bf(a.z); o[3] = f2bf(a.w);
        o[4] = f2bf(b.x); o[5] = f2bf(b.y); o[6] = f2bf(b.z); o[7] = f2bf(b.w);
        *(uint4*)&Xbf[i] = *(uint4*)o;
        return;
    }
    if (bx < 8192) {                     // ---- weight transpose+cast ----
        const int i = bx - 4096;
        const int z = i >> 10, rem = i & 1023;
        const int n0 = (rem & 31) * 64, k0 = (rem >> 5) * 64;
        const float* in;
        u16* out;
        switch (z) {
            case 0:  in = Wq; out = Wtqkv;            break;
            case 1:  in = Wk; out = Wtqkv + 4194304;  break;
            case 2:  in = Wv; out = Wtqkv + 8388608;  break;
            default: in = Wo; out = Wot;              break;
        }
        const int lr = t >> 4, lc = (t & 15) * 4;
#pragma unroll
        for (int rep = 0; rep < 4; ++rep) {
            float4 v = *(const float4*)&in[(size_t)(k0 + rep * 16 + lr) * 2048 + n0 + lc];
            tile[rep * 16 + lr][lc + 0] = v.x;
            tile[rep * 16 + lr][lc + 1] = v.y;
            tile[rep * 16 + lr][lc + 2] = v.z;
            tile[rep * 16 + lr][lc + 3] = v.w;
        }
        __syncthreads();
        const int nr = t >> 3, kc = (t & 7) * 8;
#pragma unroll
        for (int rep = 0; rep < 2; ++rep) {
            const int n = rep * 32 + nr;
            u16 o[8];
#pragma unroll
            for (int e = 0; e < 8; ++e) o[e] = f2bf(tile[kc + e][n]);
            *(uint4*)&out[(size_t)(n0 + n) * 2048 + k0 + kc] = *(uint4*)o;
        }
        return;
    }
    {                                    // ---- rope tables ----
        int idx = (bx - 8192) * 256 + t;   // 2048*64
        int pos = idx >> 6, i = idx & 63;
        float invf = __expf(-(float)i * (10.819778284410283f / 64.0f));
        float a = (float)pos * invf;
        cosb[idx] = cosf(a);
        sinb[idx] = sinf(a);
    }
}

// ---------------- GEMM 256x256, 8-phase counted-vmcnt schedule (m201 reconstruction) ------
// 2 K-tiles (BK=64) per 8-phase iteration; even tiles in buf0, odd in buf1.
// Staging unit = 8KB (1 gld16/thread), 2 units/phase:
//   ph0: Be-u01  ph1: Be-u23  ph2: Ae-q01  ph3: Ae-q23  (tile t+2)
//   ph4: Bo-u01  ph5: Bo-u23  ph6: Ao-q01  ph7: Ao-q23  (tile t+3)
// A-unit q = tile rows {32q..32q+31} u {128+32q..}; B-unit u = rows {64u..64u+63}.
// WAR: every unit's stage phase >= its old copy's last-read phase (same-phase fenced by
// lgkmcnt(0) between ds_reads and gld issue). RAW: vmcnt(6) at ph3/ph7 => units staged
// >=5 phases ago resident. Last iteration: no staging, ph3 vmcnt(0).
// Swizzle (session-verified): LDS[r][cb] = G[r][cb ^ ((r&7)<<4)], read col ^= (lane&7)<<4.
__global__ __launch_bounds__(512, 1) void gemm256(const u16* __restrict__ A,
                                                  const u16* __restrict__ Bt,
                                                  u16* __restrict__ C,
                                                  int M, int N, int K) {
    __shared__ u16 As[2][256][64];   // 64 KB
    __shared__ u16 Bs[2][256][64];   // 64 KB
    const int NI = K >> 7;                         // iterations (2 K-tiles each)
    const int cpx = gridDim.x >> 3;                // grid % 8 == 0
    const int wg = (blockIdx.x & 7) * cpx + (blockIdx.x >> 3);   // bijective XCD swizzle
    const int gm = M >> 8;
    const int bn = wg / gm, bm = wg % gm;          // consecutive wg share bn (B panel L2)
    const int tid = threadIdx.x;
    const int lane = tid & 63, w = tid >> 6;
    const int wr = w >> 2, wc = w & 3;
    const int lrow = lane & 15;
    const int sw = (lane & 7) << 4;                                  // read-side swizzle
    const int sswc = ((lane & 7) * 16) ^ ((lane >> 3) << 4);          // pre-swizzled src col
    const size_t Kb = (size_t)K * 2;
    // staging source bases (per-lane row folded in; row&7 == lane>>3 for all units)
    const char* aThr = (const char*)A +
        (size_t)(bm * 256 + ((w & 3) << 3) + (lane >> 3) + ((w >> 2) << 7)) * Kb + sswc;
    const char* bThr = (const char*)Bt +
        (size_t)(bn * 256 + (w << 3) + (lane >> 3)) * Kb + sswc;
    // staging LDS dest row bases (wave-uniform; gld16 adds lane*16)
    const int aDr = ((w & 3) << 3) + ((w >> 2) << 7);   // + 32q
    const int bDr = (w << 3);                           // + 64u

#define STAGE_A(bf, q, tile) gld16(&As[bf][32 * (q) + aDr][0], \
        aThr + (size_t)(32 * (q)) * Kb + (size_t)(tile) * 128)
#define STAGE_B(bf, u, tile) gld16(&Bs[bf][64 * (u) + bDr][0], \
        bThr + (size_t)(64 * (u)) * Kb + (size_t)(tile) * 128)

    f32x4 acc[8][4] = {};

    // prologue: tiles 0 (buf0) and 1 (buf1), canonical order; leave last 3 units in flight
#pragma unroll
    for (int u = 0; u < 4; ++u) STAGE_B(0, u, 0);
#pragma unroll
    for (int q = 0; q < 4; ++q) STAGE_A(0, q, 0);
#pragma unroll
    for (int u = 0; u < 4; ++u) STAGE_B(1, u, 1);
#pragma unroll
    for (int q = 0; q < 4; ++q) STAGE_A(1, q, 1);
    asm volatile("s_waitcnt vmcnt(6)" ::: "memory");
    asm volatile("s_barrier" ::: "memory");

    for (int it = 0; it < NI; ++it) {
        const bool more = (it + 1 < NI);
        const int te2 = 2 * it + 2, to2 = 2 * it + 3;   // tiles being staged
        short8 bfr[4][2];
#pragma unroll
        for (int ph = 0; ph < 8; ++ph) {
            const int tb = ph >> 2;        // buffer: 0 for even tile, 1 for odd
            const int q = ph & 3;
            const char* AsB = (const char*)&As[tb][0][0];
            // ds_read this phase's A quadrant (4 x b128); B frags at q==0 (8 x b128)
            short8 afr[2][2];
#pragma unroll
            for (int e = 0; e < 2; ++e)
#pragma unroll
                for (int kh = 0; kh < 2; ++kh)
                    afr[e][kh] = *(const short8*)(AsB +
                        (wr * 128 + (2 * q + e) * 16 + lrow) * 128 +
                        ((kh * 64 + (lane >> 4) * 16) ^ sw));
            if (q == 0) {
                const char* BsB = (const char*)&Bs[tb][0][0];
#pragma unroll
                for (int fn = 0; fn < 4; ++fn)
#pragma unroll
                    for (int kh = 0; kh < 2; ++kh)
                        bfr[fn][kh] = *(const short8*)(BsB +
                            (wc * 64 + fn * 16 + lrow) * 128 +
                            ((kh * 64 + (lane >> 4) * 16) ^ sw));
            }
            // fence: LDS reads complete before staging may overwrite same-phase regions
            asm volatile("s_waitcnt lgkmcnt(0)" ::: "memory");
            if (more) {
                if (ph == 0) { STAGE_B(0, 0, te2); STAGE_B(0, 1, te2); }
                if (ph == 1) { STAGE_B(0, 2, te2); STAGE_B(0, 3, te2); }
                if (ph == 2) { STAGE_A(0, 0, te2); STAGE_A(0, 1, te2); }
                if (ph == 3) { STAGE_A(0, 2, te2); STAGE_A(0, 3, te2); }
                if (ph == 4) { STAGE_B(1, 0, to2); STAGE_B(1, 1, to2); }
                if (ph == 5) { STAGE_B(1, 2, to2); STAGE_B(1, 3, to2); }
                if (ph == 6) { STAGE_A(1, 0, to2); STAGE_A(1, 1, to2); }
                if (ph == 7) { STAGE_A(1, 2, to2); STAGE_A(1, 3, to2); }
            }
            asm volatile("s_barrier" ::: "memory");
            __builtin_amdgcn_s_setprio(1);
#pragma unroll
            for (int e = 0; e < 2; ++e)
#pragma unroll
                for (int fn = 0; fn < 4; ++fn)
#pragma unroll
                    for (int kh = 0; kh < 2; ++kh)
                        acc[2 * q + e][fn] = __builtin_amdgcn_mfma_f32_16x16x32_bf16(
                            afr[e][kh], bfr[fn][kh], acc[2 * q + e][fn], 0, 0, 0);
            __builtin_amdgcn_s_setprio(0);
            if (ph == 3) {   // counted wait: prev-iter ph5-7 units resident for ph4-7
                if (more) asm volatile("s_waitcnt vmcnt(6)" ::: "memory");
                else      asm volatile("s_waitcnt vmcnt(0)" ::: "memory");
            }
            if (ph == 7 && more)   // this-iter ph0-4 units resident for next ph0-3
                asm volatile("s_waitcnt vmcnt(6)" ::: "memory");
            asm volatile("s_barrier" ::: "memory");
        }
    }
#undef STAGE_A
#undef STAGE_B

    const int crow = (lane >> 4) * 4, ccol = lane & 15;
#pragma unroll
    for (int fm = 0; fm < 8; ++fm)
#pragma unroll
        for (int fn = 0; fn < 4; ++fn)
#pragma unroll
            for (int r = 0; r < 4; ++r) {
                size_t off = (size_t)(bm * 256 + wr * 128 + fm * 16 + crow + r) * N +
                             (size_t)(bn * 256 + wc * 64 + fn * 16 + ccol);
                C[off] = f2bf(acc[fm][fn][r]);
            }
}

// ---------------- GEMM: C = A[M][K] * Bt[N][K]^T, BK=64, single-barrier double-buffer ------
// (R8-verified; used for the out-projection: 512-block grid tessellates at 2/CU)
template <bool BF16OUT>
__global__ __launch_bounds__(256) void gemm_bt(const u16* __restrict__ A,
                                               const u16* __restrict__ Bt,
                                               void* __restrict__ Cv,
                                               int M, int N, int K) {
    __shared__ u16 As[2][128][64];   // 2 x 16 KB
    __shared__ u16 Bs[2][128][64];   // 2 x 16 KB
    const int bm = blockIdx.y, bn = blockIdx.x;
    const int tid = threadIdx.x;
    const int lane = tid & 63, w = tid >> 6;
    const int wm = (w >> 1) * 64, wn = (w & 1) * 64;
    const int lrow = lane & 15;
    const int sw = (lane & 7) << 4;
    const int srl = lane >> 3;
    const int ssw = ((lane & 7) * 16) ^ (srl << 4);
    const char* AB = (const char*)A;
    const char* BB = (const char*)Bt;
    const int NT = K >> 6;
    f32x4 acc[4][4] = {};

    const char* Ab[4];
    const char* Bb[4];
#pragma unroll
    for (int i = 0; i < 4; ++i) {
        const int rb = i * 32 + w * 8;
        Ab[i] = AB + ((size_t)(bm * 128 + rb + srl) * K) * 2 + ssw;
        Bb[i] = BB + ((size_t)(bn * 128 + rb + srl) * K) * 2 + ssw;
    }

#pragma unroll
    for (int i = 0; i < 4; ++i) {
        const int rb = i * 32 + w * 8;
        gld16(&As[0][rb][0], Ab[i]);
        gld16(&Bs[0][rb][0], Bb[i]);
    }

    for (int t = 0; t < NT; ++t) {
        const int buf = t & 1;
        __syncthreads();
        if (t + 1 < NT) {
            const size_t ko = (size_t)(t + 1) * 128;
#pragma unroll
            for (int i = 0; i < 4; ++i) {
                const int rb = i * 32 + w * 8;
                gld16(&As[buf ^ 1][rb][0], Ab[i] + ko);
                gld16(&Bs[buf ^ 1][rb][0], Bb[i] + ko);
            }
        }
        const char* AsB = (const char*)&As[buf][0][0];
        const char* BsB = (const char*)&Bs[buf][0][0];
#pragma unroll
        for (int kk = 0; kk < 2; ++kk) {
            const int cb = (kk * 64 + (lane >> 4) * 16) ^ sw;
            short8 af[4], bf_[4];
#pragma unroll
            for (int i = 0; i < 4; ++i)
                af[i] = *(const short8*)(AsB + (wm + i * 16 + lrow) * 128 + cb);
#pragma unroll
            for (int j = 0; j < 4; ++j)
                bf_[j] = *(const short8*)(BsB + (wn + j * 16 + lrow) * 128 + cb);
            __builtin_amdgcn_s_setprio(1);
#pragma unroll
            for (int i = 0; i < 4; ++i)
#pragma unroll
                for (int j = 0; j < 4; ++j)
                    acc[i][j] = __builtin_amdgcn_mfma_f32_16x16x32_bf16(af[i], bf_[j], acc[i][j], 0, 0, 0);
            __builtin_amdgcn_s_setprio(0);
        }
    }
    const int crow = (lane >> 4) * 4, ccol = lane & 15;
#pragma unroll
    for (int i = 0; i < 4; ++i)
#pragma unroll
        for (int j = 0; j < 4; ++j)
#pragma unroll
            for (int r = 0; r < 4; ++r) {
                size_t off = (size_t)(bm * 128 + wm + i * 16 + crow + r) * N +
                             (size_t)(bn * 128 + wn + j * 16 + ccol);
                if (BF16OUT) ((u16*)Cv)[off] = f2bf(acc[i][j][r]);
                else         ((float*)Cv)[off] = acc[i][j][r];
            }
}

// ---------------- fused RMSNorm+RoPE (q,k) | V transpose ----------------
__global__ __launch_bounds__(256) void norm_rope_v(const u16* __restrict__ qkv,  // [4096][6144]
                                                   const float* __restrict__ qw,
                                                   const float* __restrict__ kw,
                                                   const float* __restrict__ cosb,
                                                   const float* __restrict__ sinb,
                                                   u16* __restrict__ Qout,
                                                   u16* __restrict__ Kout,
                                                   u16* __restrict__ Vt) {
    __shared__ __align__(16) char smem[17408];   // max(norm: 16416, vtr: 17408)
    const int bx = blockIdx.x;
    const int t = threadIdx.x;
    if (bx < 4096) {                     // ---- RMSNorm + RoPE ----
        float* qf = (float*)smem;                 // [2048]
        float* kf = (float*)(smem + 8192);        // [2048]
        __shared__ float red[8];
        const int r = bx;
        const int b = r >> 11, pos = r & 2047;
        const u16* row = qkv + (size_t)r * 6144;
        uint4 qv = *(const uint4*)&row[t * 8];
        uint4 kv = *(const uint4*)&row[2048 + t * 8];
        float qe[8], ke[8];
        unpack8(qv, qe);
        unpack8(kv, ke);
        float sq = 0.f, sk = 0.f;
#pragma unroll
        for (int e = 0; e < 8; ++e) {
            qf[t * 8 + e] = qe[e];
            kf[t * 8 + e] = ke[e];
            sq += qe[e] * qe[e];
            sk += ke[e] * ke[e];
        }
#pragma unroll
        for (int msk = 1; msk < 64; msk <<= 1) {
            sq += __shfl_xor(sq, msk);
            sk += __shfl_xor(sk, msk);
        }
        if ((t & 63) == 0) { red[t >> 6] = sq; red[4 + (t >> 6)] = sk; }
        __syncthreads();
        float ssq = red[0] + red[1] + red[2] + red[3];
        float ssk = red[4] + red[5] + red[6] + red[7];
        // 1/sqrt(128) * log2(e) folded into q
        const float invq = 0.12751946f / sqrtf(ssq * (1.f / 2048.f) + 1e-6f);
        const float invk = 1.0f / sqrtf(ssk * (1.f / 2048.f) + 1e-6f);
        const float* ct = cosb + pos * 64;
        const float* st = sinb + pos * 64;
        u16 qo[8], ko[8];
#pragma unroll
        for (int e = 0; e < 8; ++e) {
            int c = t * 8 + e;
            int jl = c & 127;
            int hb = c & ~127;
            int jj = jl & 63;
            float cs = ct[jj], sn = st[jj];
            int pair = hb + ((jl < 64) ? jl + 64 : jl - 64);
            float sgn = (jl < 64) ? -1.f : 1.f;
            float xq = qf[c] * qw[c], pq = qf[pair] * qw[pair];
            float xk = kf[c] * kw[c], pk = kf[pair] * kw[pair];
            qo[e] = f2bf((xq * cs + sgn * pq * sn) * invq);
            ko[e] = f2bf((xk * cs + sgn * pk * sn) * invk);
        }
        const int h = (t * 8) >> 7;
        const int j0 = (t * 8) & 127;
        size_t o = ((size_t)(b * 16 + h) * 2048 + pos) * 128 + j0;
        *(uint4*)&Qout[o] = *(uint4*)qo;
        *(uint4*)&Kout[o] = *(uint4*)ko;
        return;
    }
    {                                    // ---- V transpose ----
        u16 (*tile)[136] = (u16(*)[136])smem;     // [64][136]
        const int i = bx - 4096;          // 1024 = 32 pt * 32 bh
        const int pt = i & 31, bh = i >> 5;
        const int b = bh >> 4, h = bh & 15;
        const int pos0 = pt * 64;
        const int p = t >> 4, jc = (t & 15) * 8;
#pragma unroll
        for (int rep = 0; rep < 4; ++rep)
            *(uint4*)&tile[rep * 16 + p][jc] =
                *(const uint4*)&qkv[(size_t)(b * 2048 + pos0 + rep * 16 + p) * 6144 + 4096 + h * 128 + jc];
        __syncthreads();
        const int j = t >> 3, pc = (t & 7) * 8;
#pragma unroll
        for (int rep = 0; rep < 4; ++rep) {
            const int jj = rep * 32 + j;
            u16 tmp[8];
#pragma unroll
            for (int e = 0; e < 8; ++e) tmp[e] = tile[pc + e][jj];
            *(uint4*)&Vt[((size_t)bh * 128 + jj) * 2048 + pos0 + pc] = *(uint4*)tmp;
        }
    }
}

// ---------------- causal flash attention v7 (R10/R12-verified): swapped-QK 32x32 ----------
__global__ __launch_bounds__(256, 2) void attn_fwd(const u16* __restrict__ Qr,   // [bh][n][128]
                                                   const u16* __restrict__ Kr,   // [bh][n][128]
                                                   const u16* __restrict__ Vt,   // [bh][128][n]
                                                   u16* __restrict__ O) {        // [4096][2048]
    __shared__ u16 Ks[2][64][128];    // kv x d, 256B rows
    __shared__ u16 VsT[2][128][64];   // d x kv, 128B rows
    const int bx = blockIdx.x;        // 512
    const int g = bx >> 3;            // 0..63
    const int bh = (bx & 7) + 8 * (g & 3);                      // same-XCD grouping
    const int qt = (g < 32) ? (15 - (g >> 2)) : ((g >> 2) - 8); // big tiles first
    const int tid = threadIdx.x;
    const int lane = tid & 63, w = tid >> 6;
    const int ql = lane & 31, h = lane >> 5;
    const char* KhB = (const char*)(Kr + (size_t)bh * 2048 * 128);   // 256B rows
    const char* VhB = (const char*)(Vt + (size_t)bh * 128 * 2048);   // 4096B rows
    const u16* Qh = Qr + (size_t)bh * 2048 * 128;
    const int b = bh >> 4, hh = bh & 15;
    const int krl = lane >> 4;                  // K: 4 rows per gld
    const int ksc = (lane & 15) * 16;           // K: byte col
    const int vrl = lane >> 3;                  // V: 8 rows per gld
    const int vsc = (lane & 7) * 16;            // V: byte col
    const int swz = (ql & 7) << 4;              // read-side swizzle (row%8 == ql%8)

    const int q0w = qt * 128 + w * 32;
    const int qg = q0w + ql;                // this lane's q row
    short8 qb[8];                            // Q[qg][16s + 8h .. +7]
#pragma unroll
    for (int s = 0; s < 8; ++s)
        qb[s] = *(const short8*)&Qh[(size_t)qg * 128 + s * 16 + h * 8];

    f32x16 ot[4] = {};                      // O^T accum: dh-tile td, col q=ql
    float m = -3e38f, ls = 0.f;
    const int kend = qt * 128 + 128;

    // prologue: stage step 0 into buffer 0 (8 glds per wave)
#pragma unroll
    for (int j = 0; j < 4; ++j) {
        const int krb = w * 16 + j * 4;
        const int kr = krb + krl;
        gld16(&Ks[0][krb][0], KhB + (size_t)kr * 256 + (ksc ^ ((kr & 7) << 4)));
        const int vrb = w * 32 + j * 8;
        const int vr = vrb + vrl;
        gld16(&VsT[0][vrb][0], VhB + (size_t)vr * 4096 + (vsc ^ ((vr & 7) << 4)));
    }

    for (int k0 = 0; k0 < kend; k0 += 64) {
        const int buf = (k0 >> 6) & 1;
        __syncthreads();   // drains vmcnt: buf staged; fences WAR for buf^1
        if (k0 + 64 < kend) {   // prefetch next step into buf^1
            const int kn = k0 + 64;
#pragma unroll
            for (int j = 0; j < 4; ++j) {
                const int krb = w * 16 + j * 4;
                const int kr = krb + krl;
                gld16(&Ks[buf ^ 1][krb][0],
                      KhB + (size_t)(kn + kr) * 256 + (ksc ^ ((kr & 7) << 4)));
                const int vrb = w * 32 + j * 8;
                const int vr = vrb + vrl;
                gld16(&VsT[buf ^ 1][vrb][0],
                      VhB + (size_t)vr * 4096 + (size_t)kn * 2 + (vsc ^ ((vr & 7) << 4)));
            }
        }
        const char* KsB = (const char*)&Ks[buf][0][0];
        const char* VsB = (const char*)&VsT[buf][0][0];

        // S^T[kv][q] = K * Q^T : A = K tile rows (m=kv=ql), B = Q (n=q=ql)
        f32x16 st[2] = {};
#pragma unroll
        for (int s = 0; s < 8; ++s) {
            short8 kf0 = *(const short8*)(KsB + (size_t)ql * 256 + ((s * 32 + 16 * h) ^ swz));
            short8 kf1 = *(const short8*)(KsB + (size_t)(32 + ql) * 256 + ((s * 32 + 16 * h) ^ swz));
            st[0] = __builtin_amdgcn_mfma_f32_32x32x16_bf16(kf0, qb[s], st[0], 0, 0, 0);
            st[1] = __builtin_amdgcn_mfma_f32_32x32x16_bf16(kf1, qb[s], st[1], 0, 0, 0);
        }

        // causal mask (kv index = k0 + 32T + (reg&3) + 8*(reg>>2) + 4h; keep if <= qg)
        if (k0 + 64 > q0w) {
#pragma unroll
            for (int T = 0; T < 2; ++T)
#pragma unroll
                for (int reg = 0; reg < 16; ++reg) {
                    int c = k0 + 32 * T + (reg & 3) + 8 * (reg >> 2) + 4 * h;
                    if (c > qg) st[T][reg] = -1e30f;
                }
        }

        // row max: TREE (depth ~5)
        float mx;
        {
            float vm[16];
#pragma unroll
            for (int r = 0; r < 16; ++r) vm[r] = fmaxf(st[0][r], st[1][r]);
            float m4[4];
#pragma unroll
            for (int r = 0; r < 4; ++r)
                m4[r] = fmaxf(fmaxf(vm[r], vm[4 + r]), fmaxf(vm[8 + r], vm[12 + r]));
            mx = fmaxf(fmaxf(m4[0], m4[1]), fmaxf(m4[2], m4[3]));
            mx = fmaxf(mx, __shfl_xor(mx, 32));
        }

        // defer-max: rescale only when max grew by > 8 (log2 units; p <= 2^8 otherwise)
        if (__any(mx > m + 8.f)) {
            float mn = fmaxf(m, mx);
            float corr = exp2f(m - mn);
            m = mn;
            ls *= corr;
#pragma unroll
            for (int td = 0; td < 4; ++td)
#pragma unroll
                for (int reg = 0; reg < 16; ++reg) ot[td][reg] *= corr;
        }

        // p = exp2(s - m) in place; row-sum as TREE
        float ps;
        {
#pragma unroll
            for (int T = 0; T < 2; ++T)
#pragma unroll
                for (int reg = 0; reg < 16; ++reg)
                    st[T][reg] = exp2f(st[T][reg] - m);
            float vs[16];
#pragma unroll
            for (int r = 0; r < 16; ++r) vs[r] = st[0][r] + st[1][r];
            float s4[4];
#pragma unroll
            for (int r = 0; r < 4; ++r)
                s4[r] = (vs[r] + vs[4 + r]) + (vs[8 + r] + vs[12 + r]);
            ps = (s4[0] + s4[1]) + (s4[2] + s4[3]);
            ps += __shfl_xor(ps, 32);
        }
        ls += ps;

        // PV: O^T += V^T * P^T. Build P^T B-frags via cvt_pk + permlane32_swap.
#pragma unroll
        for (int T = 0; T < 2; ++T) {
            u32 c[4][2];
#pragma unroll
            for (int mm = 0; mm < 4; ++mm) {
                c[mm][0] = cvtpk_bf16(st[T][4 * mm + 0], st[T][4 * mm + 1]);
                c[mm][1] = cvtpk_bf16(st[T][4 * mm + 2], st[T][4 * mm + 3]);
            }
#pragma unroll
            for (int i = 0; i < 2; ++i) {
                const int ks = 2 * T + i;
                u32 a0 = c[2 * i][0], b0 = c[2 * i + 1][0];
                u32 a1 = c[2 * i][1], b1 = c[2 * i + 1][1];
                asm volatile("v_permlane32_swap_b32 %0, %1" : "+v"(a0), "+v"(b0));
                asm volatile("v_permlane32_swap_b32 %0, %1" : "+v"(a1), "+v"(b1));
                u32x4 pw = {a0, a1, b0, b1};
                short8 pf = __builtin_bit_cast(short8, pw);
#pragma unroll
                for (int td = 0; td < 4; ++td) {
                    short8 vf = *(const short8*)(VsB + (size_t)(32 * td + ql) * 128 +
                                                 ((32 * ks + 16 * h) ^ swz));
                    ot[td] = __builtin_amdgcn_mfma_f32_32x32x16_bf16(vf, pf, ot[td], 0, 0, 0);
                }
            }
        }
    }

    // epilogue: O^T lane: q = ql fixed; dh = 32td + 8g + 4h + rr
    const float inv = 1.0f / ls;
    const size_t base = ((size_t)b * 2048 + qg) * 2048 + (size_t)hh * 128;
#pragma unroll
    for (int td = 0; td < 4; ++td)
#pragma unroll
        for (int g2 = 0; g2 < 4; ++g2) {
            ushort4 o4;
            o4.x = f2bf(ot[td][4 * g2 + 0] * inv);
            o4.y = f2bf(ot[td][4 * g2 + 1] * inv);
            o4.z = f2bf(ot[td][4 * g2 + 2] * inv);
            o4.w = f2bf(ot[td][4 * g2 + 3] * inv);
            *(ushort4*)&O[base + 32 * td + 8 * g2 + 4 * h] = o4;
        }
}

extern "C" void kernel_launch(void* const* d_in, const int* in_sizes, int n_in,
                              void* d_out, int out_size, void* d_ws, size_t ws_size,
                              hipStream_t stream) {
    const float* x   = (const float*)d_in[0];
    const float* Wq  = (const float*)d_in[1];
    const float* Wk  = (const float*)d_in[2];
    const float* Wv  = (const float*)d_in[3];
    const float* Wo  = (const float*)d_in[4];
    const float* qnw = (const float*)d_in[5];
    const float* knw = (const float*)d_in[6];

    const size_t MB = 1ull << 20;
    char* ws = (char*)d_ws;
    u16* Xbf    = (u16*)(ws + 0);                 // 16 MB (reused as Qr after gemm1)
    u16* Qr     = (u16*)(ws + 0);
    u16* Wtqkv  = (u16*)(ws + 16 * MB);           // 24 MB
    u16* Wot    = (u16*)(ws + 40 * MB);           // 8 MB
    u16* QKV    = (u16*)(ws + 48 * MB);           // 48 MB (reused as attn_out)
    u16* AOut   = (u16*)(ws + 48 * MB);
    float* cosb = (float*)(ws + 96 * MB);         // 512 KB
    float* sinb = (float*)(ws + 96 * MB + 524288);// 512 KB
    u16* Kr     = (u16*)(ws + 97 * MB);           // 16 MB
    u16* Vt     = (u16*)(ws + 113 * MB);          // 16 MB (total 129 MB)

    prep_all<<<8704, 256, 0, stream>>>(x, Wq, Wk, Wv, Wo, Xbf, Wtqkv, Wot, cosb, sinb);

    // QKV: [4096,2048]@[2048,6144] -> 16x24 = 384 blocks of 256x256, 8-phase schedule
    gemm256<<<384, 512, 0, stream>>>(Xbf, Wtqkv, QKV, 4096, 6144, 2048);

    // fused: RMSNorm+RoPE (blocks 0..4095) | V transpose (blocks 4096..5119)
    norm_rope_v<<<5120, 256, 0, stream>>>(QKV, qnw, knw, cosb, sinb, Qr, Kr, Vt);

    attn_fwd<<<512, 256, 0, stream>>>(Qr, Kr, Vt, AOut);

    // out-proj: [4096,2048]@[2048,2048] -> fp32 d_out (R8 kernel, 512-block grid)
    gemm_bt<false><<<dim3(16, 32), 256, 0, stream>>>(AOut, Wot, d_out, 4096, 2048, 2048);
}

// Round 17
// 263.758 us; speedup vs baseline: 1.0584x; 1.0584x over previous
//
#include <hip/hip_runtime.h>

typedef unsigned short u16;
typedef unsigned int u32;
typedef __attribute__((ext_vector_type(8))) short short8;
typedef __attribute__((ext_vector_type(4))) float f32x4;
typedef __attribute__((ext_vector_type(16))) float f32x16;
typedef __attribute__((ext_vector_type(4))) u32 u32x4;

typedef __attribute__((address_space(3))) unsigned int as3u32;
typedef __attribute__((address_space(1))) unsigned int as1u32;

__device__ __forceinline__ void gld16(void* lds, const void* g) {
    __builtin_amdgcn_global_load_lds((as1u32*)(void*)g, (as3u32*)lds, 16, 0, 0);
}

__device__ inline float bf2f(u16 u) {
    u32 v = ((u32)u) << 16;
    return __builtin_bit_cast(float, v);
}
__device__ inline u16 f2bf(float f) {
    u32 u = __builtin_bit_cast(u32, f);
    u32 r = u + 0x7FFF + ((u >> 16) & 1);   // round-to-nearest-even
    return (u16)(r >> 16);
}
__device__ __forceinline__ u32 cvtpk_bf16(float lo, float hi) {
    u32 r;
    asm("v_cvt_pk_bf16_f32 %0, %1, %2" : "=v"(r) : "v"(lo), "v"(hi));
    return r;
}
__device__ inline void unpack8(uint4 v, float* f) {
    u32 a[4] = {v.x, v.y, v.z, v.w};
#pragma unroll
    for (int i = 0; i < 4; ++i) {
        f[2 * i]     = bf2f((u16)(a[i] & 0xffff));
        f[2 * i + 1] = bf2f((u16)(a[i] >> 16));
    }
}

// ---------------- fused prep: x cast | weight transpose+cast | rope tables ----------------
__global__ __launch_bounds__(256) void prep_all(const float* __restrict__ x,
                                                const float* __restrict__ Wq,
                                                const float* __restrict__ Wk,
                                                const float* __restrict__ Wv,
                                                const float* __restrict__ Wo,
                                                u16* __restrict__ Xbf,
                                                u16* __restrict__ Wtqkv,
                                                u16* __restrict__ Wot,
                                                float* __restrict__ cosb,
                                                float* __restrict__ sinb) {
    __shared__ float tile[64][65];
    const int bx = blockIdx.x;
    const int t = threadIdx.x;
    if (bx < 4096) {                     // ---- cast x ----
        int i = (bx * 256 + t) * 8;
        float4 a = *(const float4*)&x[i];
        float4 b = *(const float4*)&x[i + 4];
        u16 o[8];
        o[0] = f2bf(a.x); o[1] = f2bf(a.y); o[2] = f2bf(a.z); o[3] = f2bf(a.w);
        o[4] = f2bf(b.x); o[5] = f2bf(b.y); o[6] = f2bf(b.z); o[7] = f2bf(b.w);
        *(uint4*)&Xbf[i] = *(uint4*)o;
        return;
    }
    if (bx < 8192) {                     // ---- weight transpose+cast ----
        const int i = bx - 4096;
        const int z = i >> 10, rem = i & 1023;
        const int n0 = (rem & 31) * 64, k0 = (rem >> 5) * 64;
        const float* in;
        u16* out;
        switch (z) {
            case 0:  in = Wq; out = Wtqkv;            break;
            case 1:  in = Wk; out = Wtqkv + 4194304;  break;
            case 2:  in = Wv; out = Wtqkv + 8388608;  break;
            default: in = Wo; out = Wot;              break;
        }
        const int lr = t >> 4, lc = (t & 15) * 4;
#pragma unroll
        for (int rep = 0; rep < 4; ++rep) {
            float4 v = *(const float4*)&in[(size_t)(k0 + rep * 16 + lr) * 2048 + n0 + lc];
            tile[rep * 16 + lr][lc + 0] = v.x;
            tile[rep * 16 + lr][lc + 1] = v.y;
            tile[rep * 16 + lr][lc + 2] = v.z;
            tile[rep * 16 + lr][lc + 3] = v.w;
        }
        __syncthreads();
        const int nr = t >> 3, kc = (t & 7) * 8;
#pragma unroll
        for (int rep = 0; rep < 2; ++rep) {
            const int n = rep * 32 + nr;
            u16 o[8];
#pragma unroll
            for (int e = 0; e < 8; ++e) o[e] = f2bf(tile[kc + e][n]);
            *(uint4*)&out[(size_t)(n0 + n) * 2048 + k0 + kc] = *(uint4*)o;
        }
        return;
    }
    {                                    // ---- rope tables ----
        int idx = (bx - 8192) * 256 + t;   // 2048*64
        int pos = idx >> 6, i = idx & 63;
        float invf = __expf(-(float)i * (10.819778284410283f / 64.0f));
        float a = (float)pos * invf;
        cosb[idx] = cosf(a);
        sinb[idx] = sinf(a);
    }
}

// ---------------- GEMM: C = A[M][K] * Bt[N][K]^T, BK=64, single-barrier double-buffer ------
// (R8-verified: 876 TF structure ceiling; swizzled global_load_lds staging, conflicts 0)
template <bool BF16OUT>
__global__ __launch_bounds__(256) void gemm_bt(const u16* __restrict__ A,
                                               const u16* __restrict__ Bt,
                                               void* __restrict__ Cv,
                                               int M, int N, int K) {
    __shared__ u16 As[2][128][64];   // 2 x 16 KB
    __shared__ u16 Bs[2][128][64];   // 2 x 16 KB
    const int bm = blockIdx.y, bn = blockIdx.x;
    const int tid = threadIdx.x;
    const int lane = tid & 63, w = tid >> 6;
    const int wm = (w >> 1) * 64, wn = (w & 1) * 64;
    const int lrow = lane & 15;
    const int sw = (lane & 7) << 4;
    const int srl = lane >> 3;
    const int ssw = ((lane & 7) * 16) ^ (srl << 4);
    const char* AB = (const char*)A;
    const char* BB = (const char*)Bt;
    const int NT = K >> 6;
    f32x4 acc[4][4] = {};

    const char* Ab[4];
    const char* Bb[4];
#pragma unroll
    for (int i = 0; i < 4; ++i) {
        const int rb = i * 32 + w * 8;
        Ab[i] = AB + ((size_t)(bm * 128 + rb + srl) * K) * 2 + ssw;
        Bb[i] = BB + ((size_t)(bn * 128 + rb + srl) * K) * 2 + ssw;
    }

#pragma unroll
    for (int i = 0; i < 4; ++i) {
        const int rb = i * 32 + w * 8;
        gld16(&As[0][rb][0], Ab[i]);
        gld16(&Bs[0][rb][0], Bb[i]);
    }

    for (int t = 0; t < NT; ++t) {
        const int buf = t & 1;
        __syncthreads();
        if (t + 1 < NT) {
            const size_t ko = (size_t)(t + 1) * 128;
#pragma unroll
            for (int i = 0; i < 4; ++i) {
                const int rb = i * 32 + w * 8;
                gld16(&As[buf ^ 1][rb][0], Ab[i] + ko);
                gld16(&Bs[buf ^ 1][rb][0], Bb[i] + ko);
            }
        }
        const char* AsB = (const char*)&As[buf][0][0];
        const char* BsB = (const char*)&Bs[buf][0][0];
#pragma unroll
        for (int kk = 0; kk < 2; ++kk) {
            const int cb = (kk * 64 + (lane >> 4) * 16) ^ sw;
            short8 af[4], bf_[4];
#pragma unroll
            for (int i = 0; i < 4; ++i)
                af[i] = *(const short8*)(AsB + (wm + i * 16 + lrow) * 128 + cb);
#pragma unroll
            for (int j = 0; j < 4; ++j)
                bf_[j] = *(const short8*)(BsB + (wn + j * 16 + lrow) * 128 + cb);
            __builtin_amdgcn_s_setprio(1);
#pragma unroll
            for (int i = 0; i < 4; ++i)
#pragma unroll
                for (int j = 0; j < 4; ++j)
                    acc[i][j] = __builtin_amdgcn_mfma_f32_16x16x32_bf16(af[i], bf_[j], acc[i][j], 0, 0, 0);
            __builtin_amdgcn_s_setprio(0);
        }
    }
    const int crow = (lane >> 4) * 4, ccol = lane & 15;
#pragma unroll
    for (int i = 0; i < 4; ++i)
#pragma unroll
        for (int j = 0; j < 4; ++j)
#pragma unroll
            for (int r = 0; r < 4; ++r) {
                size_t off = (size_t)(bm * 128 + wm + i * 16 + crow + r) * N +
                             (size_t)(bn * 128 + wn + j * 16 + ccol);
                if (BF16OUT) ((u16*)Cv)[off] = f2bf(acc[i][j][r]);
                else         ((float*)Cv)[off] = acc[i][j][r];
            }
}

// ---------------- fused RMSNorm+RoPE (q,k) | V transpose ----------------
__global__ __launch_bounds__(256) void norm_rope_v(const u16* __restrict__ qkv,  // [4096][6144]
                                                   const float* __restrict__ qw,
                                                   const float* __restrict__ kw,
                                                   const float* __restrict__ cosb,
                                                   const float* __restrict__ sinb,
                                                   u16* __restrict__ Qout,
                                                   u16* __restrict__ Kout,
                                                   u16* __restrict__ Vt) {
    __shared__ __align__(16) char smem[17408];   // max(norm: 16416, vtr: 17408)
    const int bx = blockIdx.x;
    const int t = threadIdx.x;
    if (bx < 4096) {                     // ---- RMSNorm + RoPE ----
        float* qf = (float*)smem;                 // [2048]
        float* kf = (float*)(smem + 8192);        // [2048]
        __shared__ float red[8];
        const int r = bx;
        const int b = r >> 11, pos = r & 2047;
        const u16* row = qkv + (size_t)r * 6144;
        uint4 qv = *(const uint4*)&row[t * 8];
        uint4 kv = *(const uint4*)&row[2048 + t * 8];
        float qe[8], ke[8];
        unpack8(qv, qe);
        unpack8(kv, ke);
        float sq = 0.f, sk = 0.f;
#pragma unroll
        for (int e = 0; e < 8; ++e) {
            qf[t * 8 + e] = qe[e];
            kf[t * 8 + e] = ke[e];
            sq += qe[e] * qe[e];
            sk += ke[e] * ke[e];
        }
#pragma unroll
        for (int msk = 1; msk < 64; msk <<= 1) {
            sq += __shfl_xor(sq, msk);
            sk += __shfl_xor(sk, msk);
        }
        if ((t & 63) == 0) { red[t >> 6] = sq; red[4 + (t >> 6)] = sk; }
        __syncthreads();
        float ssq = red[0] + red[1] + red[2] + red[3];
        float ssk = red[4] + red[5] + red[6] + red[7];
        // 1/sqrt(128) * log2(e) folded into q
        const float invq = 0.12751946f / sqrtf(ssq * (1.f / 2048.f) + 1e-6f);
        const float invk = 1.0f / sqrtf(ssk * (1.f / 2048.f) + 1e-6f);
        const float* ct = cosb + pos * 64;
        const float* st = sinb + pos * 64;
        u16 qo[8], ko[8];
#pragma unroll
        for (int e = 0; e < 8; ++e) {
            int c = t * 8 + e;
            int jl = c & 127;
            int hb = c & ~127;
            int jj = jl & 63;
            float cs = ct[jj], sn = st[jj];
            int pair = hb + ((jl < 64) ? jl + 64 : jl - 64);
            float sgn = (jl < 64) ? -1.f : 1.f;
            float xq = qf[c] * qw[c], pq = qf[pair] * qw[pair];
            float xk = kf[c] * kw[c], pk = kf[pair] * kw[pair];
            qo[e] = f2bf((xq * cs + sgn * pq * sn) * invq);
            ko[e] = f2bf((xk * cs + sgn * pk * sn) * invk);
        }
        const int h = (t * 8) >> 7;
        const int j0 = (t * 8) & 127;
        size_t o = ((size_t)(b * 16 + h) * 2048 + pos) * 128 + j0;
        *(uint4*)&Qout[o] = *(uint4*)qo;
        *(uint4*)&Kout[o] = *(uint4*)ko;
        return;
    }
    {                                    // ---- V transpose ----
        u16 (*tile)[136] = (u16(*)[136])smem;     // [64][136]
        const int i = bx - 4096;          // 1024 = 32 pt * 32 bh
        const int pt = i & 31, bh = i >> 5;
        const int b = bh >> 4, h = bh & 15;
        const int pos0 = pt * 64;
        const int p = t >> 4, jc = (t & 15) * 8;
#pragma unroll
        for (int rep = 0; rep < 4; ++rep)
            *(uint4*)&tile[rep * 16 + p][jc] =
                *(const uint4*)&qkv[(size_t)(b * 2048 + pos0 + rep * 16 + p) * 6144 + 4096 + h * 128 + jc];
        __syncthreads();
        const int j = t >> 3, pc = (t & 7) * 8;
#pragma unroll
        for (int rep = 0; rep < 4; ++rep) {
            const int jj = rep * 32 + j;
            u16 tmp[8];
#pragma unroll
            for (int e = 0; e < 8; ++e) tmp[e] = tile[pc + e][jj];
            *(uint4*)&Vt[((size_t)bh * 128 + jj) * 2048 + pos0 + pc] = *(uint4*)tmp;
        }
    }
}

// ---------------- causal flash attention v7 (R10/R12-verified): swapped-QK 32x32 ----------
__global__ __launch_bounds__(256, 2) void attn_fwd(const u16* __restrict__ Qr,   // [bh][n][128]
                                                   const u16* __restrict__ Kr,   // [bh][n][128]
                                                   const u16* __restrict__ Vt,   // [bh][128][n]
                                                   u16* __restrict__ O) {        // [4096][2048]
    __shared__ u16 Ks[2][64][128];    // kv x d, 256B rows
    __shared__ u16 VsT[2][128][64];   // d x kv, 128B rows
    const int bx = blockIdx.x;        // 512
    const int g = bx >> 3;            // 0..63
    const int bh = (bx & 7) + 8 * (g & 3);                      // same-XCD grouping
    const int qt = (g < 32) ? (15 - (g >> 2)) : ((g >> 2) - 8); // big tiles first
    const int tid = threadIdx.x;
    const int lane = tid & 63, w = tid >> 6;
    const int ql = lane & 31, h = lane >> 5;
    const char* KhB = (const char*)(Kr + (size_t)bh * 2048 * 128);   // 256B rows
    const char* VhB = (const char*)(Vt + (size_t)bh * 128 * 2048);   // 4096B rows
    const u16* Qh = Qr + (size_t)bh * 2048 * 128;
    const int b = bh >> 4, hh = bh & 15;
    const int krl = lane >> 4;                  // K: 4 rows per gld
    const int ksc = (lane & 15) * 16;           // K: byte col
    const int vrl = lane >> 3;                  // V: 8 rows per gld
    const int vsc = (lane & 7) * 16;            // V: byte col
    const int swz = (ql & 7) << 4;              // read-side swizzle (row%8 == ql%8)

    const int q0w = qt * 128 + w * 32;
    const int qg = q0w + ql;                // this lane's q row
    short8 qb[8];                            // Q[qg][16s + 8h .. +7]
#pragma unroll
    for (int s = 0; s < 8; ++s)
        qb[s] = *(const short8*)&Qh[(size_t)qg * 128 + s * 16 + h * 8];

    f32x16 ot[4] = {};                      // O^T accum: dh-tile td, col q=ql
    float m = -3e38f, ls = 0.f;
    const int kend = qt * 128 + 128;

    // prologue: stage step 0 into buffer 0 (8 glds per wave)
#pragma unroll
    for (int j = 0; j < 4; ++j) {
        const int krb = w * 16 + j * 4;
        const int kr = krb + krl;
        gld16(&Ks[0][krb][0], KhB + (size_t)kr * 256 + (ksc ^ ((kr & 7) << 4)));
        const int vrb = w * 32 + j * 8;
        const int vr = vrb + vrl;
        gld16(&VsT[0][vrb][0], VhB + (size_t)vr * 4096 + (vsc ^ ((vr & 7) << 4)));
    }

    for (int k0 = 0; k0 < kend; k0 += 64) {
        const int buf = (k0 >> 6) & 1;
        __syncthreads();   // drains vmcnt: buf staged; fences WAR for buf^1
        if (k0 + 64 < kend) {   // prefetch next step into buf^1
            const int kn = k0 + 64;
#pragma unroll
            for (int j = 0; j < 4; ++j) {
                const int krb = w * 16 + j * 4;
                const int kr = krb + krl;
                gld16(&Ks[buf ^ 1][krb][0],
                      KhB + (size_t)(kn + kr) * 256 + (ksc ^ ((kr & 7) << 4)));
                const int vrb = w * 32 + j * 8;
                const int vr = vrb + vrl;
                gld16(&VsT[buf ^ 1][vrb][0],
                      VhB + (size_t)vr * 4096 + (size_t)kn * 2 + (vsc ^ ((vr & 7) << 4)));
            }
        }
        const char* KsB = (const char*)&Ks[buf][0][0];
        const char* VsB = (const char*)&VsT[buf][0][0];

        // S^T[kv][q] = K * Q^T : A = K tile rows (m=kv=ql), B = Q (n=q=ql)
        f32x16 st[2] = {};
#pragma unroll
        for (int s = 0; s < 8; ++s) {
            short8 kf0 = *(const short8*)(KsB + (size_t)ql * 256 + ((s * 32 + 16 * h) ^ swz));
            short8 kf1 = *(const short8*)(KsB + (size_t)(32 + ql) * 256 + ((s * 32 + 16 * h) ^ swz));
            st[0] = __builtin_amdgcn_mfma_f32_32x32x16_bf16(kf0, qb[s], st[0], 0, 0, 0);
            st[1] = __builtin_amdgcn_mfma_f32_32x32x16_bf16(kf1, qb[s], st[1], 0, 0, 0);
        }

        // causal mask (kv index = k0 + 32T + (reg&3) + 8*(reg>>2) + 4h; keep if <= qg)
        if (k0 + 64 > q0w) {
#pragma unroll
            for (int T = 0; T < 2; ++T)
#pragma unroll
                for (int reg = 0; reg < 16; ++reg) {
                    int c = k0 + 32 * T + (reg & 3) + 8 * (reg >> 2) + 4 * h;
                    if (c > qg) st[T][reg] = -1e30f;
                }
        }

        // row max: TREE (depth ~5)
        float mx;
        {
            float vm[16];
#pragma unroll
            for (int r = 0; r < 16; ++r) vm[r] = fmaxf(st[0][r], st[1][r]);
            float m4[4];
#pragma unroll
            for (int r = 0; r < 4; ++r)
                m4[r] = fmaxf(fmaxf(vm[r], vm[4 + r]), fmaxf(vm[8 + r], vm[12 + r]));
            mx = fmaxf(fmaxf(m4[0], m4[1]), fmaxf(m4[2], m4[3]));
            mx = fmaxf(mx, __shfl_xor(mx, 32));
        }

        // defer-max: rescale only when max grew by > 8 (log2 units; p <= 2^8 otherwise)
        if (__any(mx > m + 8.f)) {
            float mn = fmaxf(m, mx);
            float corr = exp2f(m - mn);
            m = mn;
            ls *= corr;
#pragma unroll
            for (int td = 0; td < 4; ++td)
#pragma unroll
                for (int reg = 0; reg < 16; ++reg) ot[td][reg] *= corr;
        }

        // p = exp2(s - m) in place; row-sum as TREE
        float ps;
        {
#pragma unroll
            for (int T = 0; T < 2; ++T)
#pragma unroll
                for (int reg = 0; reg < 16; ++reg)
                    st[T][reg] = exp2f(st[T][reg] - m);
            float vs[16];
#pragma unroll
            for (int r = 0; r < 16; ++r) vs[r] = st[0][r] + st[1][r];
            float s4[4];
#pragma unroll
            for (int r = 0; r < 4; ++r)
                s4[r] = (vs[r] + vs[4 + r]) + (vs[8 + r] + vs[12 + r]);
            ps = (s4[0] + s4[1]) + (s4[2] + s4[3]);
            ps += __shfl_xor(ps, 32);
        }
        ls += ps;

        // PV: O^T += V^T * P^T. Build P^T B-frags via cvt_pk + permlane32_swap.
#pragma unroll
        for (int T = 0; T < 2; ++T) {
            u32 c[4][2];
#pragma unroll
            for (int mm = 0; mm < 4; ++mm) {
                c[mm][0] = cvtpk_bf16(st[T][4 * mm + 0], st[T][4 * mm + 1]);
                c[mm][1] = cvtpk_bf16(st[T][4 * mm + 2], st[T][4 * mm + 3]);
            }
#pragma unroll
            for (int i = 0; i < 2; ++i) {
                const int ks = 2 * T + i;
                u32 a0 = c[2 * i][0], b0 = c[2 * i + 1][0];
                u32 a1 = c[2 * i][1], b1 = c[2 * i + 1][1];
                asm volatile("v_permlane32_swap_b32 %0, %1" : "+v"(a0), "+v"(b0));
                asm volatile("v_permlane32_swap_b32 %0, %1" : "+v"(a1), "+v"(b1));
                u32x4 pw = {a0, a1, b0, b1};
                short8 pf = __builtin_bit_cast(short8, pw);
#pragma unroll
                for (int td = 0; td < 4; ++td) {
                    short8 vf = *(const short8*)(VsB + (size_t)(32 * td + ql) * 128 +
                                                 ((32 * ks + 16 * h) ^ swz));
                    ot[td] = __builtin_amdgcn_mfma_f32_32x32x16_bf16(vf, pf, ot[td], 0, 0, 0);
                }
            }
        }
    }

    // epilogue: O^T lane: q = ql fixed; dh = 32td + 8g + 4h + rr
    const float inv = 1.0f / ls;
    const size_t base = ((size_t)b * 2048 + qg) * 2048 + (size_t)hh * 128;
#pragma unroll
    for (int td = 0; td < 4; ++td)
#pragma unroll
        for (int g2 = 0; g2 < 4; ++g2) {
            ushort4 o4;
            o4.x = f2bf(ot[td][4 * g2 + 0] * inv);
            o4.y = f2bf(ot[td][4 * g2 + 1] * inv);
            o4.z = f2bf(ot[td][4 * g2 + 2] * inv);
            o4.w = f2bf(ot[td][4 * g2 + 3] * inv);
            *(ushort4*)&O[base + 32 * td + 8 * g2 + 4 * h] = o4;
        }
}

extern "C" void kernel_launch(void* const* d_in, const int* in_sizes, int n_in,
                              void* d_out, int out_size, void* d_ws, size_t ws_size,
                              hipStream_t stream) {
    const float* x   = (const float*)d_in[0];
    const float* Wq  = (const float*)d_in[1];
    const float* Wk  = (const float*)d_in[2];
    const float* Wv  = (const float*)d_in[3];
    const float* Wo  = (const float*)d_in[4];
    const float* qnw = (const float*)d_in[5];
    const float* knw = (const float*)d_in[6];

    const size_t MB = 1ull << 20;
    char* ws = (char*)d_ws;
    u16* Xbf    = (u16*)(ws + 0);                 // 16 MB (reused as Qr after gemm1)
    u16* Qr     = (u16*)(ws + 0);
    u16* Wtqkv  = (u16*)(ws + 16 * MB);           // 24 MB
    u16* Wot    = (u16*)(ws + 40 * MB);           // 8 MB
    u16* QKV    = (u16*)(ws + 48 * MB);           // 48 MB (reused as attn_out)
    u16* AOut   = (u16*)(ws + 48 * MB);
    float* cosb = (float*)(ws + 96 * MB);         // 512 KB
    float* sinb = (float*)(ws + 96 * MB + 524288);// 512 KB
    u16* Kr     = (u16*)(ws + 97 * MB);           // 16 MB
    u16* Vt     = (u16*)(ws + 113 * MB);          // 16 MB (total 129 MB)

    prep_all<<<8704, 256, 0, stream>>>(x, Wq, Wk, Wv, Wo, Xbf, Wtqkv, Wot, cosb, sinb);

    gemm_bt<true><<<dim3(48, 32), 256, 0, stream>>>(Xbf, Wtqkv, (void*)QKV, 4096, 6144, 2048);

    // fused: RMSNorm+RoPE (blocks 0..4095) | V transpose (blocks 4096..5119)
    norm_rope_v<<<5120, 256, 0, stream>>>(QKV, qnw, knw, cosb, sinb, Qr, Kr, Vt);

    attn_fwd<<<512, 256, 0, stream>>>(Qr, Kr, Vt, AOut);

    gemm_bt<false><<<dim3(16, 32), 256, 0, stream>>>(AOut, Wot, d_out, 4096, 2048, 2048);
}